// Round 3
// baseline (2019.080 us; speedup 1.0000x reference)
//
#include <hip/hip_runtime.h>
#include <math.h>

#define NTRAJ 32
#define TLEN  64
#define BATCH (NTRAJ*TLEN)   // 2048

__device__ __forceinline__ float eluf(float x){ return x > 0.f ? x : expm1f(x); }
__device__ __forceinline__ float sigmf(float x){ return 1.f/(1.f+expf(-x)); }

// ---------------- conv1: NHWC (C=4) input -> NHWC [2048][42][42][32] ----------
__global__ __launch_bounds__(256) void conv1_kernel(
    const float* __restrict__ in,   // [2048][84][84][4]
    const float* __restrict__ w,    // [3][3][4][32] HWIO
    const float* __restrict__ b,    // [32]
    float* __restrict__ out)        // [2048][42][42][32]
{
    int bid = blockIdx.x;
    bid = (bid & 7)*1764 + (bid >> 3);           // XCD chunk swizzle (14112%8==0)
    int pos = bid*256 + threadIdx.x;             // 3,612,672 exactly
    int n   = pos / (42*42);
    int rem = pos % (42*42);
    int oy  = rem / 42, ox = rem % 42;
    float acc[32];
    #pragma unroll
    for(int o=0;o<32;o++) acc[o] = b[o];
    for(int ky=0; ky<3; ky++){
        int iy = 2*oy + ky;                      // pad_before = 0 (84->42 SAME)
        if(iy >= 84) continue;
        for(int kx=0; kx<3; kx++){
            int ix = 2*ox + kx;
            if(ix >= 84) continue;
            float4 v = *(const float4*)(in + (((n*84 + iy)*84) + ix)*4);
            const float* wq = w + (ky*3 + kx)*128;   // [ci][32]
            #pragma unroll
            for(int o=0;o<32;o++) acc[o] += v.x*wq[o];
            #pragma unroll
            for(int o=0;o<32;o++) acc[o] += v.y*wq[32+o];
            #pragma unroll
            for(int o=0;o<32;o++) acc[o] += v.z*wq[64+o];
            #pragma unroll
            for(int o=0;o<32;o++) acc[o] += v.w*wq[96+o];
        }
    }
    float4* op = (float4*)(out + (size_t)pos*32);
    #pragma unroll
    for(int q=0;q<8;q++)
        op[q] = make_float4(eluf(acc[4*q]), eluf(acc[4*q+1]),
                            eluf(acc[4*q+2]), eluf(acc[4*q+3]));
}

// ---------------- conv2/3/4: NHWC 32ch -> NHWC 32ch ---------------------------
template<int IH, int IW, int OH, int OW, int PB>
__global__ __launch_bounds__(256) void convN_kernel(
    const float* __restrict__ in,   // [BATCH][IH][IW][32]
    const float* __restrict__ w,    // [3][3][32][32] HWIO
    const float* __restrict__ b,    // [32]
    float* __restrict__ out)        // [BATCH][OH][OW][32]
{
    int bid = blockIdx.x;
    const int cpx = gridDim.x >> 3;              // all conv grids %8 == 0
    bid = (bid & 7)*cpx + (bid >> 3);            // XCD chunk swizzle
    int pos = bid*256 + threadIdx.x;
    if(pos >= BATCH*OH*OW) return;
    int n   = pos / (OH*OW);
    int rem = pos % (OH*OW);
    int oy  = rem / OW, ox = rem % OW;
    float acc[32];
    #pragma unroll
    for(int o=0;o<32;o++) acc[o] = b[o];
    for(int ky=0; ky<3; ky++){
        int iy = 2*oy + ky - PB;
        if(iy < 0 || iy >= IH) continue;
        for(int kx=0; kx<3; kx++){
            int ix = 2*ox + kx - PB;
            if(ix < 0 || ix >= IW) continue;
            const float4* ip = (const float4*)(in + ((size_t)(n*IH + iy)*IW + ix)*32);
            const float* wp = w + (ky*3 + kx)*1024;  // [ci][32]
            #pragma unroll
            for(int c4=0;c4<8;c4++){
                float4 x = ip[c4];
                const float* wq = wp + c4*128;       // uniform -> s_load
                #pragma unroll
                for(int o=0;o<32;o++) acc[o] += x.x*wq[o];
                #pragma unroll
                for(int o=0;o<32;o++) acc[o] += x.y*wq[32+o];
                #pragma unroll
                for(int o=0;o<32;o++) acc[o] += x.z*wq[64+o];
                #pragma unroll
                for(int o=0;o<32;o++) acc[o] += x.w*wq[96+o];
            }
        }
    }
    float4* op = (float4*)(out + (size_t)pos*32);
    #pragma unroll
    for(int q=0;q<8;q++)
        op[q] = make_float4(eluf(acc[4*q]), eluf(acc[4*q+1]),
                            eluf(acc[4*q+2]), eluf(acc[4*q+3]));
}

// ---------------- conv4 NHWC ([nt][feat]) -> A_T[feat=1152][row=2048] ---------
__global__ __launch_bounds__(256) void relayout_kernel(
    const float* __restrict__ p4,   // [2048(nt)][1152(f)]
    float* __restrict__ at)         // [1152][2048], row r = t*32+n
{
    int i = blockIdx.x*256 + threadIdx.x;   // 2,359,296 exactly
    int f = i >> 11, r = i & 2047;          // write coalesced over r
    int tt = r >> 5, n = r & 31;            // r = t*32 + n
    int nt = n*64 + tt;
    at[i] = p4[nt*1152 + f];
}

// ---------------- gate pre-projection: gx[r][1024] = A_T^T @ Wx + b ----------
__global__ __launch_bounds__(256) void gx_gemm_kernel(
    const float* __restrict__ at,   // [1152][2048]
    const float* __restrict__ lw,   // [1408][1024] (rows 0..1151 = Wx)
    const float* __restrict__ lb,   // [1024]
    float* __restrict__ gx,         // [2048][1024], row r = t*32+n
    unsigned int* __restrict__ bar) // 128 flag words (stride 32) for lstm_coop
{
    if(blockIdx.x == 0 && blockIdx.y == 0 && threadIdx.x < 128)
        bar[threadIdx.x*32] = 0u;
    int lane = threadIdx.x & 63;
    int wv   = threadIdx.x >> 6;
    int r0   = blockIdx.x * 16;                    // grid.x = 128
    int oc   = blockIdx.y*256 + wv*64 + lane;      // grid.y = 4
    float acc[16];
    float bias = lb[oc];
    #pragma unroll
    for(int i=0;i<16;i++) acc[i] = bias;
    #pragma unroll 4
    for(int k=0;k<1152;k++){
        float wval = lw[k*1024 + oc];              // coalesced v-load
        const float* ap = at + k*2048 + r0;        // uniform -> s_load_dwordx16
        #pragma unroll
        for(int i=0;i<16;i++) acc[i] += ap[i] * wval;
    }
    #pragma unroll
    for(int i=0;i<16;i++) gx[(r0+i)*1024 + oc] = acc[i];  // coalesced
}

// ---------------- cooperative weight-stationary LSTM, 128 WGs -----------------
// WG g owns units [2g, 2g+2): 8 gate columns gcol = gate*256 + 2g + uu.
// Thread = one output (traj n = t>>3, col cidx = t&7), full K=256.
// Per k4: exactly 2 conflict-free ds_read_b128 (h row, w col) -> per-CU LDS
// issue is 3x lower than the 32-WG version, spread over 4x more CUs.
__global__ __launch_bounds__(256) void lstm_coop_kernel(
    const float* __restrict__ gx,   // [2048][1024], row = st*32+n (bias folded)
    const float* __restrict__ lw,   // [1408][1024]; rows 1152.. = Wh
    const float* __restrict__ c0,   // [32][256]
    const float* __restrict__ h0,   // [32][256]
    float* __restrict__ feats,      // [2048][256], row = n*64+st
    float* __restrict__ hbuf,       // [2][32][256] double-buffered h broadcast
    unsigned int* __restrict__ bar) // [128] flags, stride 32 uints (pre-zeroed)
{
    // pads (+4 floats/row) put row r on bank-quad (r*4)%32 -> 8 distinct rows
    // hit 8 distinct bank quads for any fixed k4 -> conflict-free b128 reads.
    __shared__ float hs[32*260];    // h staged, [n][260]
    __shared__ float wl[8*260];     // Wh slice, [cidx][260] (col-major in k)
    __shared__ float gl[32*9];      // gate buffer [n][9]

    const int wg = blockIdx.x;      // 0..127, owns units 2wg, 2wg+1
    const int t  = threadIdx.x;
    const int n    = t >> 3;        // traj 0..31
    const int cidx = t & 7;         // local col 0..7
    const int gcol = (cidx>>1)*256 + wg*2 + (cidx&1);   // global gate column
    const float* wh = lw + 1152*1024;

    // ---- one-time: Wh slice (256 x 8 cols) -> LDS
    #pragma unroll
    for(int i=0;i<8;i++){
        int e = t + 256*i;                  // 2048 elements
        int k = e >> 3, cc = e & 7;
        int gc = (cc>>1)*256 + wg*2 + (cc&1);
        wl[cc*260 + k] = wh[k*1024 + gc];
    }
    // ---- persistent cell state: threads t<64 own (un = t>>1, uu = t&1)
    const int un = t >> 1, uu = t & 1;
    float cst = (t < 64) ? c0[un*256 + wg*2 + uu] : 0.f;

    float4* hs4 = (float4*)hs;      // row stride 65 float4s

    for(int st=0; st<64; ++st){
        // ---- stage full h(t-1) into LDS (coalesced 16B/lane, padded rows)
        const float4* hp4 = (const float4*)((st == 0) ? h0 : (hbuf + ((st&1)^1)*8192));
        #pragma unroll
        for(int i=0;i<8;i++){
            int q = t + 256*i;              // 2048 float4s
            int row = q >> 6, col4 = q & 63;
            hs4[row*65 + col4] = hp4[q];
        }
        // issue gx load early; consumed after the matvec loop
        float gxv = gx[(st*32 + n)*1024 + gcol];
        __syncthreads();
        // ---- matvec: 1 output/thread; h & w reads both 8-distinct broadcasts
        float a = 0.f;
        const float4* hr = (const float4*)&hs[n*260];
        const float4* wr = (const float4*)&wl[cidx*260];
        #pragma unroll 8
        for(int k4=0;k4<64;k4++){
            float4 hv = hr[k4];
            float4 wv = wr[k4];
            a += hv.x*wv.x + hv.y*wv.y + hv.z*wv.z + hv.w*wv.w;
        }
        gl[n*9 + cidx] = a + gxv;
        __syncthreads();
        // ---- update: t<64 owns (un, uu)
        if(t < 64){
            float i_ = gl[un*9 +     uu];
            float j_ = gl[un*9 + 2 + uu];
            float f_ = gl[un*9 + 4 + uu];
            float o_ = gl[un*9 + 6 + uu];
            cst = cst*sigmf(f_ + 1.f) + sigmf(i_)*tanhf(j_);
            float h = tanhf(cst)*sigmf(o_);
            int col = wg*2 + uu;
            hbuf[(st&1)*8192 + un*256 + col] = h;
            feats[(un*64 + st)*256 + col]    = h;
        }
        // ---- distributed device barrier: own-flag release, parallel polls
        if(st != 63){
            __syncthreads();                // all h stores vmcnt-drained
            if(t == 0)
                __hip_atomic_store(bar + wg*32, (unsigned)(st+1),
                                   __ATOMIC_RELEASE, __HIP_MEMORY_SCOPE_AGENT);
            if(t < 128){
                unsigned tgt = (unsigned)(st+1);
                unsigned spins = 0;
                while(__hip_atomic_load(bar + t*32, __ATOMIC_ACQUIRE,
                                        __HIP_MEMORY_SCOPE_AGENT) < tgt){
                    __builtin_amdgcn_s_sleep(1);
                    if(++spins > 20000000u) break;   // failsafe: no hard hang
                }
            }
            __syncthreads();
        }
    }
}

// ---------------- final FC: logits[p][18] = feats[p] @ fc_w + fc_b ----------
__global__ __launch_bounds__(64) void fc_kernel(
    const float* __restrict__ feats, const float* __restrict__ fw,
    const float* __restrict__ fb,    float* __restrict__ out)
{
    __shared__ float h[256];
    int p = blockIdx.x, t = threadIdx.x;
    *(float4*)&h[t*4] = *(const float4*)(feats + p*256 + t*4);
    __syncthreads();
    if(t < 18){
        float acc = fb[t];
        for(int k=0;k<256;k++) acc += h[k]*fw[k*18 + t];
        out[p*18 + t] = acc;
    }
}

extern "C" void kernel_launch(void* const* d_in, const int* in_sizes, int n_in,
                              void* d_out, int out_size, void* d_ws, size_t ws_size,
                              hipStream_t stream) {
    const float* inp = (const float*)d_in[0];
    const float* w1  = (const float*)d_in[1];  const float* b1 = (const float*)d_in[2];
    const float* w2  = (const float*)d_in[3];  const float* b2 = (const float*)d_in[4];
    const float* w3  = (const float*)d_in[5];  const float* b3 = (const float*)d_in[6];
    const float* w4  = (const float*)d_in[7];  const float* b4 = (const float*)d_in[8];
    const float* lw  = (const float*)d_in[9];  const float* lb = (const float*)d_in[10];
    const float* fw  = (const float*)d_in[11]; const float* fb = (const float*)d_in[12];
    const float* c0  = (const float*)d_in[13]; const float* h0 = (const float*)d_in[14];
    float* out = (float*)d_out;
    float* ws  = (float*)d_ws;

    const size_t n1 = (size_t)32*3612672;   // conv1 out (NHWC, same float count)
    const size_t n3 = (size_t)32*247808;    // conv3 out
    const size_t n4 = (size_t)32*73728;     // conv4 out

    float* p1 = ws;
    float* p2 = p1 + n1;                    // conv2 out (28.9M floats)
    float* p3 = ws;                         // reuse p1 region (conv3 reads only p2)
    float* p4 = p3 + n3;
    float* at = p4 + n4;                    // [1152][2048]
    float* gxb   = at  + (size_t)1152*2048; // [2048][1024]
    float* feats = gxb + (size_t)2048*1024; // [2048][256]
    float* hbuf  = feats + (size_t)2048*256;          // [2][32][256]
    unsigned int* bar = (unsigned int*)(hbuf + 2*32*256);  // [128] stride-32 flags

    conv1_kernel<<<14112,256,0,stream>>>(inp, w1, b1, p1);
    convN_kernel<42,42,21,21,0><<<3528,256,0,stream>>>(p1, w2, b2, p2);
    convN_kernel<21,21,11,11,1><<<968,256,0,stream>>>(p2, w3, b3, p3);
    convN_kernel<11,11, 6, 6,1><<<288,256,0,stream>>>(p3, w4, b4, p4);
    relayout_kernel<<<9216,256,0,stream>>>(p4, at);
    gx_gemm_kernel<<<dim3(128,4),256,0,stream>>>(at, lw, lb, gxb, bar);
    lstm_coop_kernel<<<128,256,0,stream>>>(gxb, lw, c0, h0, feats, hbuf, bar);
    fc_kernel<<<2048,64,0,stream>>>(feats, fw, fb, out);
}